// Round 6
// baseline (284.871 us; speedup 1.0000x reference)
//
#include <hip/hip_runtime.h>

#define DIM 384      // LN dim
#define RD  16       // reduced dim
#define PD  128      // pair_dim
#define NN  512      // max n rows staged in LDS
#define LN_EPS 1e-5f

typedef float fx4 __attribute__((ext_vector_type(4)));

// ---------------- Kernel A: LayerNorm + Linear(384->16) for x and y rows ----
__global__ __launch_bounds__(128) void ln_reduce_kernel(
    const float* __restrict__ x, const float* __restrict__ y,
    const float* __restrict__ gamma, const float* __restrict__ beta,
    const float* __restrict__ w_red, const float* __restrict__ b_red,
    float* __restrict__ xr, float* __restrict__ yr, int M)
{
  int row = blockIdx.x;
  const float* src;
  float* dst;
  if (row < M) { src = x + (size_t)row * DIM;       dst = xr + (size_t)row * RD; }
  else         { src = y + (size_t)(row - M) * DIM; dst = yr + (size_t)(row - M) * RD; }

  int t = threadIdx.x;
  float v[3];
#pragma unroll
  for (int k = 0; k < 3; ++k) v[k] = src[t + k * 128];

  __shared__ float red[2];
  __shared__ float nrm[DIM];

  float s = v[0] + v[1] + v[2];
#pragma unroll
  for (int off = 32; off; off >>= 1) s += __shfl_down(s, off);
  int wave = t >> 6, lane = t & 63;
  if (lane == 0) red[wave] = s;
  __syncthreads();
  float mu = (red[0] + red[1]) * (1.0f / DIM);
  __syncthreads();

  float d0 = v[0] - mu, d1 = v[1] - mu, d2 = v[2] - mu;
  float s2 = d0 * d0 + d1 * d1 + d2 * d2;
#pragma unroll
  for (int off = 32; off; off >>= 1) s2 += __shfl_down(s2, off);
  if (lane == 0) red[wave] = s2;
  __syncthreads();
  float var = (red[0] + red[1]) * (1.0f / DIM);
  float rsig = rsqrtf(var + LN_EPS);

#pragma unroll
  for (int k = 0; k < 3; ++k) {
    int d = t + k * 128;
    nrm[d] = (v[k] - mu) * rsig * gamma[d] + beta[d];
  }
  __syncthreads();

  int j  = t >> 3;
  int k0 = t & 7;
  float p = 0.f;
  for (int e = k0; e < DIM; e += 8)
    p += nrm[e] * w_red[e * RD + j];
  p += __shfl_xor(p, 1);
  p += __shfl_xor(p, 2);
  p += __shfl_xor(p, 4);
  if (k0 == 0) dst[j] = p + b_red[j];
}

// ---------------- Kernel B body (shared by A/B/C variants) ------------------
// MODE 0: nt store, linear n.  MODE 1: plain store, linear n.
// MODE 2: nt store, per-block rotated n-start (de-aliases the 256KB-stride
//         write cursors across blocks).
template<int REPS, int MODE>
__device__ __forceinline__ void opm_body(
    const float* __restrict__ xr, const float* __restrict__ yr,
    const float* __restrict__ w_out, const float* __restrict__ b_out,
    float* __restrict__ out, int N)
{
  __shared__ float Vm[RD][PD];        // 8 KB
  __shared__ float yrs[NN * RD];      // 32 KB
  __shared__ float xm[RD];

  int m = blockIdx.x;
  int t = threadIdx.x;

  if (t < RD) xm[t] = xr[(size_t)m * RD + t];

  {
    fx4* d = (fx4*)yrs;
    const fx4* s4 = (const fx4*)yr;
    int total = N * RD / 4;
    for (int idx = t; idx < total; idx += 512) d[idx] = s4[idx];
  }
  __syncthreads();

  {
    int p  = t & 127;
    int j0 = (t >> 7) * 4;
#pragma unroll
    for (int jj = 0; jj < 4; ++jj) {
      int j = j0 + jj;
      float acc = 0.f;
#pragma unroll
      for (int i = 0; i < RD; ++i)
        acc += xm[i] * w_out[(size_t)(i * RD + j) * PD + p];
      Vm[j][p] = acc;
    }
  }
  __syncthreads();

  int p4 = (t & 31) * 4;
  int g  = t >> 5;

  fx4 w[RD];
#pragma unroll
  for (int j = 0; j < RD; ++j) w[j] = *(const fx4*)&Vm[j][p4];
  fx4 bo = *(const fx4*)&b_out[p4];

  float* obase = out + (size_t)m * N * PD + p4;
  int base = (MODE == 2) ? ((m * 131) & (N - 1)) : 0;

#pragma unroll 1
  for (int rep = 0; rep < REPS; ++rep) {
    asm volatile("" ::: "memory");   // keep each rep's stores live
#pragma unroll 2
    for (int i = 0; i < N / 16; ++i) {
      int n = (base + i * 16 + g) & (N - 1);
      float yv[RD];
#pragma unroll
      for (int k = 0; k < 4; ++k)
        *(fx4*)&yv[k * 4] = *(const fx4*)&yrs[n * RD + k * 4];

      fx4 a0 = bo, a1 = (fx4)(0.f);
#pragma unroll
      for (int j = 0; j < 8; ++j) {
        a0 += yv[j]     * w[j];
        a1 += yv[j + 8] * w[j + 8];
      }
      fx4 acc = a0 + a1;
      if (MODE == 1)
        *(fx4*)(obase + (size_t)n * PD) = acc;
      else
        __builtin_nontemporal_store(acc, (fx4*)(obase + (size_t)n * PD));
    }
  }
}

__global__ __launch_bounds__(512) void opm_nt3(
    const float* __restrict__ xr, const float* __restrict__ yr,
    const float* __restrict__ w_out, const float* __restrict__ b_out,
    float* __restrict__ out, int N)
{ opm_body<3, 0>(xr, yr, w_out, b_out, out, N); }

__global__ __launch_bounds__(512) void opm_plain4(
    const float* __restrict__ xr, const float* __restrict__ yr,
    const float* __restrict__ w_out, const float* __restrict__ b_out,
    float* __restrict__ out, int N)
{ opm_body<4, 1>(xr, yr, w_out, b_out, out, N); }

__global__ __launch_bounds__(512) void opm_rot4(
    const float* __restrict__ xr, const float* __restrict__ yr,
    const float* __restrict__ w_out, const float* __restrict__ b_out,
    float* __restrict__ out, int N)
{ opm_body<4, 2>(xr, yr, w_out, b_out, out, N); }

extern "C" void kernel_launch(void* const* d_in, const int* in_sizes, int n_in,
                              void* d_out, int out_size, void* d_ws, size_t ws_size,
                              hipStream_t stream) {
  const float* x        = (const float*)d_in[0];
  const float* y        = (const float*)d_in[1];
  const float* ln_gamma = (const float*)d_in[2];
  const float* ln_beta  = (const float*)d_in[3];
  const float* w_red    = (const float*)d_in[4];
  const float* b_red    = (const float*)d_in[5];
  const float* w_out    = (const float*)d_in[6];
  const float* b_out    = (const float*)d_in[7];
  float* out = (float*)d_out;

  int M = in_sizes[0] / DIM;   // 512
  int N = in_sizes[1] / DIM;   // 512

  float* xr = (float*)d_ws;            // M*16 floats
  float* yr = xr + (size_t)M * RD;     // N*16 floats

  ln_reduce_kernel<<<M + N, 128, 0, stream>>>(x, y, ln_gamma, ln_beta,
                                              w_red, b_red, xr, yr, M);

  // Diagnostic A/B/C: all three compute identical values; final output is
  // written (identically) by the last. Each is REP-inflated to surface in
  // rocprof top-5 with its own counters.
  opm_nt3   <<<M, 512, 0, stream>>>(xr, yr, w_out, b_out, out, N);
  opm_plain4<<<M, 512, 0, stream>>>(xr, yr, w_out, b_out, out, N);
  opm_rot4  <<<M, 512, 0, stream>>>(xr, yr, w_out, b_out, out, N);
}

// Round 7
// 54.009 us; speedup vs baseline: 5.2745x; 5.2745x over previous
//
#include <hip/hip_runtime.h>

#define DIM 384      // LN dim
#define RD  16       // reduced dim
#define PD  128      // pair_dim
#define NH  256      // n rows per block (N/2 split)
#define LN_EPS 1e-5f

typedef float fx4 __attribute__((ext_vector_type(4)));

// ---------------- Kernel A: LayerNorm + Linear(384->16) for x and y rows ----
__global__ __launch_bounds__(128) void ln_reduce_kernel(
    const float* __restrict__ x, const float* __restrict__ y,
    const float* __restrict__ gamma, const float* __restrict__ beta,
    const float* __restrict__ w_red, const float* __restrict__ b_red,
    float* __restrict__ xr, float* __restrict__ yr, int M)
{
  int row = blockIdx.x;
  const float* src;
  float* dst;
  if (row < M) { src = x + (size_t)row * DIM;       dst = xr + (size_t)row * RD; }
  else         { src = y + (size_t)(row - M) * DIM; dst = yr + (size_t)(row - M) * RD; }

  int t = threadIdx.x;
  float v[3];
#pragma unroll
  for (int k = 0; k < 3; ++k) v[k] = src[t + k * 128];

  __shared__ float red[2];
  __shared__ float nrm[DIM];

  float s = v[0] + v[1] + v[2];
#pragma unroll
  for (int off = 32; off; off >>= 1) s += __shfl_down(s, off);
  int wave = t >> 6, lane = t & 63;
  if (lane == 0) red[wave] = s;
  __syncthreads();
  float mu = (red[0] + red[1]) * (1.0f / DIM);
  __syncthreads();

  float d0 = v[0] - mu, d1 = v[1] - mu, d2 = v[2] - mu;
  float s2 = d0 * d0 + d1 * d1 + d2 * d2;
#pragma unroll
  for (int off = 32; off; off >>= 1) s2 += __shfl_down(s2, off);
  if (lane == 0) red[wave] = s2;
  __syncthreads();
  float var = (red[0] + red[1]) * (1.0f / DIM);
  float rsig = rsqrtf(var + LN_EPS);

#pragma unroll
  for (int k = 0; k < 3; ++k) {
    int d = t + k * 128;
    nrm[d] = (v[k] - mu) * rsig * gamma[d] + beta[d];
  }
  __syncthreads();

  int j  = t >> 3;
  int k0 = t & 7;
  float p = 0.f;
  for (int e = k0; e < DIM; e += 8)
    p += nrm[e] * w_red[e * RD + j];
  p += __shfl_xor(p, 1);
  p += __shfl_xor(p, 2);
  p += __shfl_xor(p, 4);
  if (k0 == 0) dst[j] = p + b_red[j];
}

// ---------------- Kernel B: block = (n-half, m); plain stores; 4 blocks/CU --
// Vm[j,p] = sum_i xr[m,i] * w_out[i*16+j, p]   (built once per block)
// out[m,n,p] = b_out[p] + sum_j yr[n,j] * Vm[j,p]
__global__ __launch_bounds__(512) void opm_kernel(
    const float* __restrict__ xr, const float* __restrict__ yr,
    const float* __restrict__ w_out, const float* __restrict__ b_out,
    float* __restrict__ out, int N)
{
  __shared__ float Vm[RD][PD];        // 8 KB
  __shared__ float yrs[NH * RD];      // 16 KB
  __shared__ float xm[RD];

  int m  = blockIdx.y;
  int n0 = blockIdx.x * NH;
  int t  = threadIdx.x;

  if (t < RD) xm[t] = xr[(size_t)m * RD + t];

  // stage yr half: NH*RD = 4096 floats = 1024 fx4, 2 per thread
  {
    fx4* d = (fx4*)yrs;
    const fx4* s4 = (const fx4*)(yr + (size_t)n0 * RD);
    d[t]       = s4[t];
    d[t + 512] = s4[t + 512];
  }
  __syncthreads();  // xm + yrs ready

  // build Vm
  {
    int p  = t & 127;
    int j0 = (t >> 7) * 4;
#pragma unroll
    for (int jj = 0; jj < 4; ++jj) {
      int j = j0 + jj;
      float acc = 0.f;
#pragma unroll
      for (int i = 0; i < RD; ++i)
        acc += xm[i] * w_out[(size_t)(i * RD + j) * PD + p];
      Vm[j][p] = acc;
    }
  }
  __syncthreads();

  int p4 = (t & 31) * 4;
  int g  = t >> 5;                 // 0..15

  fx4 w[RD];
#pragma unroll
  for (int j = 0; j < RD; ++j) w[j] = *(const fx4*)&Vm[j][p4];
  fx4 bo = *(const fx4*)&b_out[p4];

  float* obase = out + ((size_t)m * N + n0) * PD + p4;

#pragma unroll 2
  for (int n = g; n < NH; n += 16) {
    float yv[RD];
#pragma unroll
    for (int k = 0; k < 4; ++k)
      *(fx4*)&yv[k * 4] = *(const fx4*)&yrs[n * RD + k * 4];

    fx4 a0 = bo, a1 = (fx4)(0.f);
#pragma unroll
    for (int j = 0; j < 8; ++j) {
      a0 += yv[j]     * w[j];
      a1 += yv[j + 8] * w[j + 8];
    }
    fx4 acc = a0 + a1;
    *(fx4*)(obase + (size_t)n * PD) = acc;   // plain store
  }
}

extern "C" void kernel_launch(void* const* d_in, const int* in_sizes, int n_in,
                              void* d_out, int out_size, void* d_ws, size_t ws_size,
                              hipStream_t stream) {
  const float* x        = (const float*)d_in[0];
  const float* y        = (const float*)d_in[1];
  const float* ln_gamma = (const float*)d_in[2];
  const float* ln_beta  = (const float*)d_in[3];
  const float* w_red    = (const float*)d_in[4];
  const float* b_red    = (const float*)d_in[5];
  const float* w_out    = (const float*)d_in[6];
  const float* b_out    = (const float*)d_in[7];
  float* out = (float*)d_out;

  int M = in_sizes[0] / DIM;   // 512
  int N = in_sizes[1] / DIM;   // 512

  float* xr = (float*)d_ws;            // M*16 floats
  float* yr = xr + (size_t)M * RD;     // N*16 floats

  ln_reduce_kernel<<<M + N, 128, 0, stream>>>(x, y, ln_gamma, ln_beta,
                                              w_red, b_red, xr, yr, M);

  dim3 grid(N / NH, M);
  opm_kernel<<<grid, 512, 0, stream>>>(xr, yr, w_out, b_out, out, N);
}

// Round 8
// 51.869 us; speedup vs baseline: 5.4921x; 1.0412x over previous
//
#include <hip/hip_runtime.h>

#define DIM 384      // LN dim
#define RD  16       // reduced dim
#define PD  128      // pair_dim
#define NN  512      // max n rows staged in LDS
#define LN_EPS 1e-5f

typedef float fx4 __attribute__((ext_vector_type(4)));

// ---------------- Kernel A: LayerNorm + Linear(384->16) for x and y rows ----
__global__ __launch_bounds__(128) void ln_reduce_kernel(
    const float* __restrict__ x, const float* __restrict__ y,
    const float* __restrict__ gamma, const float* __restrict__ beta,
    const float* __restrict__ w_red, const float* __restrict__ b_red,
    float* __restrict__ xr, float* __restrict__ yr, int M)
{
  int row = blockIdx.x;
  const float* src;
  float* dst;
  if (row < M) { src = x + (size_t)row * DIM;       dst = xr + (size_t)row * RD; }
  else         { src = y + (size_t)(row - M) * DIM; dst = yr + (size_t)(row - M) * RD; }

  int t = threadIdx.x;
  float v[3];
#pragma unroll
  for (int k = 0; k < 3; ++k) v[k] = src[t + k * 128];

  __shared__ float red[2];
  __shared__ float nrm[DIM];

  float s = v[0] + v[1] + v[2];
#pragma unroll
  for (int off = 32; off; off >>= 1) s += __shfl_down(s, off);
  int wave = t >> 6, lane = t & 63;
  if (lane == 0) red[wave] = s;
  __syncthreads();
  float mu = (red[0] + red[1]) * (1.0f / DIM);
  __syncthreads();

  float d0 = v[0] - mu, d1 = v[1] - mu, d2 = v[2] - mu;
  float s2 = d0 * d0 + d1 * d1 + d2 * d2;
#pragma unroll
  for (int off = 32; off; off >>= 1) s2 += __shfl_down(s2, off);
  if (lane == 0) red[wave] = s2;
  __syncthreads();
  float var = (red[0] + red[1]) * (1.0f / DIM);
  float rsig = rsqrtf(var + LN_EPS);

#pragma unroll
  for (int k = 0; k < 3; ++k) {
    int d = t + k * 128;
    nrm[d] = (v[k] - mu) * rsig * gamma[d] + beta[d];
  }
  __syncthreads();

  int j  = t >> 3;
  int k0 = t & 7;
  float p = 0.f;
  for (int e = k0; e < DIM; e += 8)
    p += nrm[e] * w_red[e * RD + j];
  p += __shfl_xor(p, 1);
  p += __shfl_xor(p, 2);
  p += __shfl_xor(p, 4);
  if (k0 == 0) dst[j] = p + b_red[j];
}

// ---------------- Kernel A2: vm[m][j][p] = sum_i xr[m,i]*w_out[i*16+j,p] ----
__global__ __launch_bounds__(256) void vm_kernel(
    const float* __restrict__ xr, const float* __restrict__ w_out,
    float* __restrict__ vm)
{
  int m = blockIdx.x;
  int t = threadIdx.x;
  __shared__ float xm[RD];
  if (t < RD) xm[t] = xr[(size_t)m * RD + t];
  __syncthreads();
  int p  = t & 127;
  int jh = t >> 7;          // 0 or 1
#pragma unroll
  for (int jj = 0; jj < 8; ++jj) {
    int j = jh * 8 + jj;
    float acc = 0.f;
#pragma unroll
    for (int i = 0; i < RD; ++i)
      acc += xm[i] * w_out[(size_t)(i * RD + j) * PD + p];
    vm[(size_t)m * RD * PD + j * PD + p] = acc;
  }
}

// ---------------- Kernel B: one block per m; w[] in REGISTERS from global ---
// out[m,n,p] = b_out[p] + sum_j yr[n,j] * vm[m,j,p]
// GLOBALW=1: w from precomputed vm (global, register-resident).
// GLOBALW=0: fallback — build Vm in LDS, pin into regs via asm ds_read_b128.
template<int GLOBALW>
__global__ __launch_bounds__(512) void opm_kernel(
    const float* __restrict__ vm_or_xr, const float* __restrict__ yr,
    const float* __restrict__ w_out, const float* __restrict__ b_out,
    float* __restrict__ out, int N)
{
  __shared__ float yrs[NN * RD];      // 32 KB

  int m = blockIdx.x;
  int t = threadIdx.x;

  // stage yr: N*RD floats as fx4
  {
    fx4* d = (fx4*)yrs;
    const fx4* s4 = (const fx4*)yr;
    int total = N * RD / 4;
    for (int idx = t; idx < total; idx += 512) d[idx] = s4[idx];
  }

  int p4 = (t & 31) * 4;
  int g  = t >> 5;

  fx4 w[RD];

  if (GLOBALW) {
    const float* vb = vm_or_xr + (size_t)m * RD * PD;   // vm_or_xr = vm
#pragma unroll
    for (int j = 0; j < RD; ++j) w[j] = *(const fx4*)&vb[j * PD + p4];
    __syncthreads();  // yrs ready
  } else {
    __shared__ float Vm[RD][PD];      // 8 KB
    __shared__ float xm[RD];
    if (t < RD) xm[t] = vm_or_xr[(size_t)m * RD + t];   // vm_or_xr = xr
    __syncthreads();
    {
      int p  = t & 127;
      int j0 = (t >> 7) * 4;
#pragma unroll
      for (int jj = 0; jj < 4; ++jj) {
        int j = j0 + jj;
        float acc = 0.f;
#pragma unroll
        for (int i = 0; i < RD; ++i)
          acc += xm[i] * w_out[(size_t)(i * RD + j) * PD + p];
        Vm[j][p] = acc;
      }
    }
    __syncthreads();
    // pin Vm rows into registers via asm ds_read_b128 (not rematerializable)
#pragma unroll
    for (int j = 0; j < RD; ++j) {
      unsigned off = (unsigned)(uintptr_t)&Vm[j][p4];
      asm volatile("ds_read_b128 %0, %1" : "=v"(w[j]) : "v"(off));
    }
    asm volatile("s_waitcnt lgkmcnt(0)" ::: "memory");
    __builtin_amdgcn_sched_barrier(0);
  }

  fx4 bo = *(const fx4*)&b_out[p4];
  float* obase = out + (size_t)m * N * PD + p4;

#pragma unroll 2
  for (int n = g; n < N; n += 16) {
    float yv[RD];
#pragma unroll
    for (int k = 0; k < 4; ++k)
      *(fx4*)&yv[k * 4] = *(const fx4*)&yrs[n * RD + k * 4];

    fx4 a0 = bo, a1 = (fx4)(0.f);
#pragma unroll
    for (int j = 0; j < 8; ++j) {
      a0 += yv[j]     * w[j];
      a1 += yv[j + 8] * w[j + 8];
    }
    fx4 acc = a0 + a1;
    *(fx4*)(obase + (size_t)n * PD) = acc;   // plain store
  }
}

extern "C" void kernel_launch(void* const* d_in, const int* in_sizes, int n_in,
                              void* d_out, int out_size, void* d_ws, size_t ws_size,
                              hipStream_t stream) {
  const float* x        = (const float*)d_in[0];
  const float* y        = (const float*)d_in[1];
  const float* ln_gamma = (const float*)d_in[2];
  const float* ln_beta  = (const float*)d_in[3];
  const float* w_red    = (const float*)d_in[4];
  const float* b_red    = (const float*)d_in[5];
  const float* w_out    = (const float*)d_in[6];
  const float* b_out    = (const float*)d_in[7];
  float* out = (float*)d_out;

  int M = in_sizes[0] / DIM;   // 512
  int N = in_sizes[1] / DIM;   // 512

  float* xr = (float*)d_ws;                 // M*16
  float* yr = xr + (size_t)M * RD;          // N*16
  float* vm = yr + (size_t)N * RD;          // M*16*128 = 4 MB

  size_t need = ((size_t)M * RD + (size_t)N * RD + (size_t)M * RD * PD) * 4;

  ln_reduce_kernel<<<M + N, 128, 0, stream>>>(x, y, ln_gamma, ln_beta,
                                              w_red, b_red, xr, yr, M);

  if (ws_size >= need) {
    vm_kernel<<<M, 256, 0, stream>>>(xr, w_out, vm);
    opm_kernel<1><<<M, 512, 0, stream>>>(vm, yr, w_out, b_out, out, N);
  } else {
    opm_kernel<0><<<M, 512, 0, stream>>>(xr, yr, w_out, b_out, out, N);
  }
}

// Round 9
// 45.957 us; speedup vs baseline: 6.1986x; 1.1286x over previous
//
#include <hip/hip_runtime.h>

#define DIM 384      // LN dim
#define RD  16       // reduced dim
#define PD  128      // pair_dim
#define NN  512      // max n rows staged in LDS
#define LN_EPS 1e-5f

typedef float fx4 __attribute__((ext_vector_type(4)));

// ---------------- Kernel A: LayerNorm + Linear(384->16) for x and y rows ----
__global__ __launch_bounds__(128) void ln_reduce_kernel(
    const float* __restrict__ x, const float* __restrict__ y,
    const float* __restrict__ gamma, const float* __restrict__ beta,
    const float* __restrict__ w_red, const float* __restrict__ b_red,
    float* __restrict__ xr, float* __restrict__ yr, int M)
{
  int row = blockIdx.x;
  const float* src;
  float* dst;
  if (row < M) { src = x + (size_t)row * DIM;       dst = xr + (size_t)row * RD; }
  else         { src = y + (size_t)(row - M) * DIM; dst = yr + (size_t)(row - M) * RD; }

  int t = threadIdx.x;
  float v[3];
#pragma unroll
  for (int k = 0; k < 3; ++k) v[k] = src[t + k * 128];

  __shared__ float red[2];
  __shared__ float nrm[DIM];

  float s = v[0] + v[1] + v[2];
#pragma unroll
  for (int off = 32; off; off >>= 1) s += __shfl_down(s, off);
  int wave = t >> 6, lane = t & 63;
  if (lane == 0) red[wave] = s;
  __syncthreads();
  float mu = (red[0] + red[1]) * (1.0f / DIM);
  __syncthreads();

  float d0 = v[0] - mu, d1 = v[1] - mu, d2 = v[2] - mu;
  float s2 = d0 * d0 + d1 * d1 + d2 * d2;
#pragma unroll
  for (int off = 32; off; off >>= 1) s2 += __shfl_down(s2, off);
  if (lane == 0) red[wave] = s2;
  __syncthreads();
  float var = (red[0] + red[1]) * (1.0f / DIM);
  float rsig = rsqrtf(var + LN_EPS);

#pragma unroll
  for (int k = 0; k < 3; ++k) {
    int d = t + k * 128;
    nrm[d] = (v[k] - mu) * rsig * gamma[d] + beta[d];
  }
  __syncthreads();

  int j  = t >> 3;
  int k0 = t & 7;
  float p = 0.f;
  for (int e = k0; e < DIM; e += 8)
    p += nrm[e] * w_red[e * RD + j];
  p += __shfl_xor(p, 1);
  p += __shfl_xor(p, 2);
  p += __shfl_xor(p, 4);
  if (k0 == 0) dst[j] = p + b_red[j];
}

// ---------------- Kernel B: one block per m, write contiguous out[m,:,:] ----
// Vm[j,p] = sum_i xr[m,i] * w_out[i*16+j, p]   (built once per block)
// out[m,n,p] = b_out[p] + sum_j yr[n,j] * Vm[j,p]
// __launch_bounds__(512, 4): VGPR cap 128 so w[16] (64 VGPR) stays
// register-resident — at 52 VGPR (R5) the compiler remat'd w from LDS every
// iteration, capping the store stream at ~4.4 TB/s via LDS-read bandwidth.
__global__ __launch_bounds__(512, 4) void opm_kernel(
    const float* __restrict__ xr, const float* __restrict__ yr,
    const float* __restrict__ w_out, const float* __restrict__ b_out,
    float* __restrict__ out, int N)
{
  __shared__ float Vm[RD][PD];        // 8 KB
  __shared__ float yrs[NN * RD];      // 32 KB
  __shared__ float xm[RD];

  int m = blockIdx.x;
  int t = threadIdx.x;

  if (t < RD) xm[t] = xr[(size_t)m * RD + t];

  // stage yr: N*RD floats as fx4
  {
    fx4* d = (fx4*)yrs;
    const fx4* s4 = (const fx4*)yr;
    int total = N * RD / 4;
    for (int idx = t; idx < total; idx += 512) d[idx] = s4[idx];
  }
  __syncthreads();  // xm ready

  // build Vm
  {
    int p  = t & 127;
    int j0 = (t >> 7) * 4;
#pragma unroll
    for (int jj = 0; jj < 4; ++jj) {
      int j = j0 + jj;
      float acc = 0.f;
#pragma unroll
      for (int i = 0; i < RD; ++i)
        acc += xm[i] * w_out[(size_t)(i * RD + j) * PD + p];
      Vm[j][p] = acc;
    }
  }
  __syncthreads();

  int p4 = (t & 31) * 4;
  int g  = t >> 5;

  fx4 w[RD];
#pragma unroll
  for (int j = 0; j < RD; ++j) w[j] = *(const fx4*)&Vm[j][p4];
  fx4 bo = *(const fx4*)&b_out[p4];

  float* obase = out + (size_t)m * N * PD + p4;

  for (int n = g; n < N; n += 16) {
    float yv[RD];
#pragma unroll
    for (int k = 0; k < 4; ++k)
      *(fx4*)&yv[k * 4] = *(const fx4*)&yrs[n * RD + k * 4];

    // two independent accumulators: FMA chain depth 8
    fx4 a0 = bo, a1 = (fx4)(0.f);
#pragma unroll
    for (int j = 0; j < 8; ++j) {
      a0 += yv[j]     * w[j];
      a1 += yv[j + 8] * w[j + 8];
    }
    fx4 acc = a0 + a1;
    *(fx4*)(obase + (size_t)n * PD) = acc;   // plain store
  }
}

extern "C" void kernel_launch(void* const* d_in, const int* in_sizes, int n_in,
                              void* d_out, int out_size, void* d_ws, size_t ws_size,
                              hipStream_t stream) {
  const float* x        = (const float*)d_in[0];
  const float* y        = (const float*)d_in[1];
  const float* ln_gamma = (const float*)d_in[2];
  const float* ln_beta  = (const float*)d_in[3];
  const float* w_red    = (const float*)d_in[4];
  const float* b_red    = (const float*)d_in[5];
  const float* w_out    = (const float*)d_in[6];
  const float* b_out    = (const float*)d_in[7];
  float* out = (float*)d_out;

  int M = in_sizes[0] / DIM;   // 512
  int N = in_sizes[1] / DIM;   // 512

  float* xr = (float*)d_ws;            // M*16 floats
  float* yr = xr + (size_t)M * RD;     // N*16 floats

  ln_reduce_kernel<<<M + N, 128, 0, stream>>>(x, y, ln_gamma, ln_beta,
                                              w_red, b_red, xr, yr, M);

  opm_kernel<<<M, 512, 0, stream>>>(xr, yr, w_out, b_out, out, N);
}